// Round 1
// baseline (431.275 us; speedup 1.0000x reference)
//
#include <hip/hip_runtime.h>

#define T_TOK 8192
#define H_DIM 4096
#define O_DIM 4096
#define R_RANK 16
#define N_AD 8

#define TB_S 32     // tokens per shrink block
#define HC 256      // h-chunk staged per iteration
#define TB_E 32     // tokens per expand block
#define OB 1024     // output columns per expand block

// ---------------- sort: bucket tokens by adapter ----------------
__global__ void sort_kernel(const int* __restrict__ idx,
                            int* __restrict__ list, int* __restrict__ base) {
    __shared__ int cnt[N_AD], cur[N_AD];
    const int tid = threadIdx.x;
    if (tid < N_AD) cnt[tid] = 0;
    __syncthreads();
    for (int t = tid; t < T_TOK; t += blockDim.x) atomicAdd(&cnt[idx[t]], 1);
    __syncthreads();
    if (tid == 0) {
        int s = 0;
        for (int a = 0; a < N_AD; ++a) { base[a] = s; cur[a] = s; s += cnt[a]; }
        base[N_AD] = s;
    }
    __syncthreads();
    for (int t = tid; t < T_TOK; t += blockDim.x) {
        int slot = atomicAdd(&cur[idx[t]], 1);
        list[slot] = t;
    }
}

// ---------------- shrink: V[t][16] = x[t] @ A[a] ----------------
// grid: (ceil(T/TB_S), 1, N_AD), 256 threads.
// thread org: hs = tid>>3 (32 h-segments), tg = tid&7 (8 groups of 4 tokens).
// Each thread accumulates vacc[4 tokens][16 r] over its h-subset
// (h = hh*32 + hs within each chunk -> A reads conflict-free with stride-20 pad).
__global__ __launch_bounds__(256, 2) void shrink_kernel(
    const float* __restrict__ x, const float* __restrict__ lora_a,
    const int* __restrict__ list, const int* __restrict__ base,
    float* __restrict__ V) {
    const int a = blockIdx.z;
    const int s0 = base[a], s1 = base[a + 1];
    const int start = s0 + blockIdx.x * TB_S;
    if (start >= s1) return;
    const int nt = min(TB_S, s1 - start);

    __shared__ float x_t[TB_S][HC + 1];     // pad +1: 2-way max on scalar reads
    __shared__ float a_t[HC][20];           // stride 20 floats: conflict-free b128
    __shared__ float red2[4][8][4][16];     // cross-wave reduction buffer
    __shared__ int toks[TB_S];

    const int tid = threadIdx.x;
    const int hs = tid >> 3;
    const int tg = tid & 7;

    if (tid < TB_S) toks[tid] = (tid < nt) ? list[start + tid] : -1;
    __syncthreads();

    float vacc[4][16];
    #pragma unroll
    for (int i = 0; i < 4; ++i)
        #pragma unroll
        for (int r = 0; r < 16; ++r) vacc[i][r] = 0.f;

    const float* Abase = lora_a + (size_t)a * H_DIM * R_RANK;

    for (int h0 = 0; h0 < H_DIM; h0 += HC) {
        // stage x tile: 32 rows x 256 cols, coalesced float4, scalar LDS stores (padded rows)
        #pragma unroll
        for (int k = 0; k < 8; ++k) {
            int flat = k * 256 + tid;      // 0..2047
            int row = flat >> 6, col4 = flat & 63;
            int t = toks[row];
            float4 vx = make_float4(0.f, 0.f, 0.f, 0.f);
            if (t >= 0) vx = *(const float4*)&x[(size_t)t * H_DIM + h0 + (col4 << 2)];
            float* dst = &x_t[row][col4 << 2];
            dst[0] = vx.x; dst[1] = vx.y; dst[2] = vx.z; dst[3] = vx.w;
        }
        // stage A chunk: 256 h x 16 r
        #pragma unroll
        for (int k = 0; k < 4; ++k) {
            int flat = k * 256 + tid;      // 0..1023
            int h = flat >> 2, q = flat & 3;
            *(float4*)&a_t[h][q << 2] =
                *(const float4*)&Abase[(size_t)(h0 + h) * R_RANK + (q << 2)];
        }
        __syncthreads();

        #pragma unroll
        for (int hh = 0; hh < 8; ++hh) {
            const int h = (hh << 5) + hs;  // interleaved segments
            const float4 a0 = *(const float4*)&a_t[h][0];
            const float4 a1 = *(const float4*)&a_t[h][4];
            const float4 a2 = *(const float4*)&a_t[h][8];
            const float4 a3 = *(const float4*)&a_t[h][12];
            #pragma unroll
            for (int i = 0; i < 4; ++i) {
                const float xv = x_t[(tg << 2) + i][h];
                vacc[i][0]  += xv * a0.x; vacc[i][1]  += xv * a0.y;
                vacc[i][2]  += xv * a0.z; vacc[i][3]  += xv * a0.w;
                vacc[i][4]  += xv * a1.x; vacc[i][5]  += xv * a1.y;
                vacc[i][6]  += xv * a1.z; vacc[i][7]  += xv * a1.w;
                vacc[i][8]  += xv * a2.x; vacc[i][9]  += xv * a2.y;
                vacc[i][10] += xv * a2.z; vacc[i][11] += xv * a2.w;
                vacc[i][12] += xv * a3.x; vacc[i][13] += xv * a3.y;
                vacc[i][14] += xv * a3.z; vacc[i][15] += xv * a3.w;
            }
        }
        __syncthreads();
    }

    // reduce over 32 h-segments: shuffle over in-wave hs (lane bits 3..5), then LDS over 4 waves
    #pragma unroll
    for (int i = 0; i < 4; ++i)
        #pragma unroll
        for (int r = 0; r < 16; ++r) {
            float f = vacc[i][r];
            f += __shfl_xor(f, 8);
            f += __shfl_xor(f, 16);
            f += __shfl_xor(f, 32);
            vacc[i][r] = f;
        }
    const int lane = tid & 63, w = tid >> 6;
    if ((lane >> 3) == 0) {                // one lane per tg per wave
        #pragma unroll
        for (int i = 0; i < 4; ++i)
            #pragma unroll
            for (int q = 0; q < 4; ++q)
                *(float4*)&red2[w][tg][i][q << 2] =
                    make_float4(vacc[i][(q << 2)], vacc[i][(q << 2) + 1],
                                vacc[i][(q << 2) + 2], vacc[i][(q << 2) + 3]);
    }
    __syncthreads();
    if (tid < 128) {
        const int tl = tid >> 2, q = tid & 3;
        const int tg2 = tl >> 2, i2 = tl & 3;
        float4 s = make_float4(0.f, 0.f, 0.f, 0.f);
        #pragma unroll
        for (int w2 = 0; w2 < 4; ++w2) {
            const float4 p = *(const float4*)&red2[w2][tg2][i2][q << 2];
            s.x += p.x; s.y += p.y; s.z += p.z; s.w += p.w;
        }
        const int t = toks[tl];
        if (t >= 0) *(float4*)&V[(size_t)t * R_RANK + (q << 2)] = s;
    }
}

// ---------------- expand: out[t] = result[t] + V[t] @ B[a] ----------------
// grid: (ceil(T/TB_E), O/OB, N_AD), 256 threads; each thread owns 1 float4 of o,
// holds B[16][o4] in registers, streams 32 result rows.
__global__ __launch_bounds__(256, 2) void expand_kernel(
    const float* __restrict__ result, const float* __restrict__ lora_b,
    const float* __restrict__ V, const int* __restrict__ list,
    const int* __restrict__ base, float* __restrict__ out) {
    const int a = blockIdx.z;
    const int s0 = base[a], s1 = base[a + 1];
    const int start = s0 + blockIdx.x * TB_E;
    if (start >= s1) return;
    const int nt = min(TB_E, s1 - start);
    const int tid = threadIdx.x;

    __shared__ float v_lds[TB_E][16];
    __shared__ int toks[TB_E];
    if (tid < TB_E) toks[tid] = (tid < nt) ? list[start + tid] : -1;
    __syncthreads();
    if (tid < 128) {
        const int tl = tid >> 2, q = tid & 3;
        const int t = toks[tl];
        float4 val = make_float4(0.f, 0.f, 0.f, 0.f);
        if (t >= 0) val = *(const float4*)&V[(size_t)t * R_RANK + (q << 2)];
        *(float4*)&v_lds[tl][q << 2] = val;
    }

    const size_t o0 = (size_t)blockIdx.y * OB + ((size_t)tid << 2);
    const float* Bb = lora_b + (size_t)a * R_RANK * O_DIM + o0;
    float4 b[16];
    #pragma unroll
    for (int r = 0; r < 16; ++r) b[r] = *(const float4*)&Bb[(size_t)r * O_DIM];
    __syncthreads();

    for (int tl = 0; tl < nt; ++tl) {
        const int t = toks[tl];
        float4 acc = *(const float4*)&result[(size_t)t * O_DIM + o0];
        float vs[16];
        #pragma unroll
        for (int q = 0; q < 4; ++q)
            *(float4*)&vs[q << 2] = *(const float4*)&v_lds[tl][q << 2];
        #pragma unroll
        for (int r = 0; r < 16; ++r) {
            acc.x += vs[r] * b[r].x; acc.y += vs[r] * b[r].y;
            acc.z += vs[r] * b[r].z; acc.w += vs[r] * b[r].w;
        }
        *(float4*)&out[(size_t)t * O_DIM + o0] = acc;
    }
}

extern "C" void kernel_launch(void* const* d_in, const int* in_sizes, int n_in,
                              void* d_out, int out_size, void* d_ws, size_t ws_size,
                              hipStream_t stream) {
    const float* result = (const float*)d_in[0];
    const float* x      = (const float*)d_in[1];
    const float* lora_a = (const float*)d_in[2];
    const float* lora_b = (const float*)d_in[3];
    const int*   aidx   = (const int*)d_in[4];
    float* out = (float*)d_out;

    float* V   = (float*)d_ws;                                  // T*16 f32 = 512 KB
    int* list  = (int*)((char*)d_ws + (size_t)T_TOK * R_RANK * 4);      // T ints
    int* base  = (int*)((char*)list + (size_t)T_TOK * 4);               // 9 ints

    sort_kernel<<<1, 256, 0, stream>>>(aidx, list, base);
    shrink_kernel<<<dim3((T_TOK + TB_S - 1) / TB_S, 1, N_AD), 256, 0, stream>>>(
        x, lora_a, list, base, V);
    expand_kernel<<<dim3((T_TOK + TB_E - 1) / TB_E, O_DIM / OB, N_AD), 256, 0, stream>>>(
        result, lora_b, V, list, base, out);
}